// Round 5
// baseline (1031.391 us; speedup 1.0000x reference)
//
#include <hip/hip_runtime.h>

#define F_IN 512
#define F_HID 16
#define F_OUT 7
#define BUCKET 128          // nodes per bucket
#define LB 7                // log2(BUCKET)
#define TRASH 128           // LDS trash row for sentinel pad edges
#define PADV 128            // packed sentinel: src=0, dl=TRASH
#define CHUNK 8192          // edges per partition block
#define AST 17              // LDS pad stride, 16-col tile
#define AST2 9              // LDS pad stride, 8-col tile
#define MAXNB 1024          // max buckets supported by scan/hist

typedef int   int4v   __attribute__((ext_vector_type(4)));
typedef float float4v __attribute__((ext_vector_type(4)));
typedef unsigned int uint4v __attribute__((ext_vector_type(4)));

static __device__ __forceinline__ unsigned short f2bf(float f) {   // RNE
    unsigned int u = __float_as_uint(f);
    u += 0x7FFFu + ((u >> 16) & 1u);
    return (unsigned short)(u >> 16);
}
static __device__ __forceinline__ float bf2f(unsigned short s) {
    return __uint_as_float((unsigned int)s << 16);
}

// ---------------- zero int array ----------------
__global__ void k_zero(int* __restrict__ p, int n) {
    int i = blockIdx.x * blockDim.x + threadIdx.x;
    if (i < n) p[i] = 0;
}

// ---------------- bucket histogram (per-block LDS, then global merge) ----------------
__global__ void k_bhist(const int* __restrict__ dst, int* __restrict__ bucket_cnt, int E, int NB) {
    __shared__ int hist[MAXNB];
    int t = threadIdx.x;
    for (int i = t; i < NB; i += 256) hist[i] = 0;
    __syncthreads();
    int base = blockIdx.x * CHUNK;
#pragma unroll
    for (int i = 0; i < CHUNK / 256; ++i) {
        int e = base + i * 256 + t;
        if (e < E) atomicAdd(&hist[__builtin_nontemporal_load(dst + e) >> LB], 1);
    }
    __syncthreads();
    for (int i = t; i < NB; i += 256)
        if (hist[i]) atomicAdd(&bucket_cnt[i], hist[i]);
}

// -------- exclusive scan of 4-aligned bucket counts + write sentinel pads --------
__global__ void k_bscan(const int* __restrict__ bucket_cnt, int* __restrict__ bucket_base,
                        int* __restrict__ cursor, int* __restrict__ bedges, int NB) {
    __shared__ int sm[MAXNB];
    int t = threadIdx.x;                       // 1024 threads
    int c = (t < NB) ? bucket_cnt[t] : 0;
    int ca = (c + 3) & ~3;                     // segment length padded to 4
    sm[t] = ca;
    __syncthreads();
    for (int off = 1; off < MAXNB; off <<= 1) {
        int v = sm[t];
        int add = (t >= off) ? sm[t - off] : 0;
        __syncthreads();
        sm[t] = v + add;
        __syncthreads();
    }
    if (t < NB) {
        int base = sm[t] - ca;                 // exclusive prefix (4-aligned)
        bucket_base[t] = base;
        cursor[t] = base;
        for (int i = c; i < ca; ++i) bedges[base + i] = PADV;   // sentinel tail
    }
}

// ---------------- partition: segmented placement of packed edges ----------------
__global__ void k_place(const int* __restrict__ src, const int* __restrict__ dst,
                        int* __restrict__ cursor, int* __restrict__ bedges, int E, int NB) {
    __shared__ int hist[MAXNB];
    __shared__ int lcur[MAXNB];
    int t = threadIdx.x;
    for (int i = t; i < NB; i += 256) hist[i] = 0;
    __syncthreads();
    int base = blockIdx.x * CHUNK;
#pragma unroll
    for (int i = 0; i < CHUNK / 256; ++i) {
        int e = base + i * 256 + t;
        if (e < E) atomicAdd(&hist[__builtin_nontemporal_load(dst + e) >> LB], 1);
    }
    __syncthreads();
    for (int i = t; i < NB; i += 256)
        lcur[i] = hist[i] ? atomicAdd(&cursor[i], hist[i]) : 0;
    __syncthreads();
#pragma unroll
    for (int i = 0; i < CHUNK / 256; ++i) {
        int e = base + i * 256 + t;
        if (e < E) {
            int d = __builtin_nontemporal_load(dst + e);
            int s = __builtin_nontemporal_load(src + e);
            int b = d >> LB;
            int pos = atomicAdd(&lcur[b], 1);
            __builtin_nontemporal_store((s << 8) | (d & (BUCKET - 1)), bedges + pos);
        }
    }
}

// ---------------- per-bucket degree histogram -> dinv ----------------
__global__ void k_bdeg_dinv(const int* __restrict__ bucket_base, const int* __restrict__ bucket_cnt,
                            const int* __restrict__ bedges, float* __restrict__ dinv, int n) {
    __shared__ int cnt[TRASH + 4];             // index 128 absorbs sentinels
    int b = blockIdx.x, t = threadIdx.x;       // 256 threads
    for (int i = t; i < TRASH + 4; i += 256) cnt[i] = 0;
    __syncthreads();
    int start = bucket_base[b], ne = bucket_cnt[b];
    int nq = (ne + 3) >> 2;
    for (int qi = t; qi < nq; qi += 256) {
        int4v q = __builtin_nontemporal_load((const int4v*)(bedges + start + (qi << 2)));
        atomicAdd(&cnt[q.x & 255], 1);
        atomicAdd(&cnt[q.y & 255], 1);
        atomicAdd(&cnt[q.z & 255], 1);
        atomicAdd(&cnt[q.w & 255], 1);
    }
    __syncthreads();
    int node = b * BUCKET + t;
    if (t < BUCKET && node < n) dinv[node] = rsqrtf((float)(cnt[t] + 1));  // +1 self-loop
}

// -------- GEMM1: h1b = bf16( dinv[r] * (x @ W1) ), one row per thread --------
__global__ void k_gemm1(const float* __restrict__ x, const float* __restrict__ W,
                        const float* __restrict__ dinv, unsigned short* __restrict__ h1b, int n) {
    int r = blockIdx.x * blockDim.x + threadIdx.x;
    if (r >= n) return;
    float acc[F_HID];
#pragma unroll
    for (int c = 0; c < F_HID; ++c) acc[c] = 0.0f;
    const float4v* xr = (const float4v*)(x + (size_t)r * F_IN);
    for (int k4 = 0; k4 < F_IN / 4; ++k4) {
        float4v xv = __builtin_nontemporal_load(xr + k4);   // x is stream-once: keep out of caches
        int k = k4 * 4;
#pragma unroll
        for (int c = 0; c < F_HID; ++c) {
            acc[c] = fmaf(xv.x, W[(k + 0) * F_HID + c], acc[c]);
            acc[c] = fmaf(xv.y, W[(k + 1) * F_HID + c], acc[c]);
            acc[c] = fmaf(xv.z, W[(k + 2) * F_HID + c], acc[c]);
            acc[c] = fmaf(xv.w, W[(k + 3) * F_HID + c], acc[c]);
        }
    }
    float dv = dinv[r];
    uint4v w0, w1;
    w0.x = (unsigned)f2bf(dv * acc[0]) | ((unsigned)f2bf(dv * acc[1]) << 16);
    w0.y = (unsigned)f2bf(dv * acc[2]) | ((unsigned)f2bf(dv * acc[3]) << 16);
    w0.z = (unsigned)f2bf(dv * acc[4]) | ((unsigned)f2bf(dv * acc[5]) << 16);
    w0.w = (unsigned)f2bf(dv * acc[6]) | ((unsigned)f2bf(dv * acc[7]) << 16);
    w1.x = (unsigned)f2bf(dv * acc[8]) | ((unsigned)f2bf(dv * acc[9]) << 16);
    w1.y = (unsigned)f2bf(dv * acc[10]) | ((unsigned)f2bf(dv * acc[11]) << 16);
    w1.z = (unsigned)f2bf(dv * acc[12]) | ((unsigned)f2bf(dv * acc[13]) << 16);
    w1.w = (unsigned)f2bf(dv * acc[14]) | ((unsigned)f2bf(dv * acc[15]) << 16);
    uint4v* o = (uint4v*)(h1b + (size_t)r * F_HID);
    o[0] = w0;
    o[1] = w1;
}

// ------ agg layer 1: block(1024)/bucket, bf16 gathers (32B/edge, L2-resident) ------
__global__ __launch_bounds__(1024) void k_agg1(
        const int* __restrict__ bucket_base, const int* __restrict__ bucket_cnt,
        const int* __restrict__ bedges, const unsigned short* __restrict__ h1b,
        const float* __restrict__ dinv, float* __restrict__ agg1, int n) {
    __shared__ float acc[(BUCKET + 1) * AST];       // row 128 = trash
    int b = blockIdx.x, t = threadIdx.x;
    for (int i = t; i < (BUCKET + 1) * AST; i += 1024) acc[i] = 0.0f;
    __syncthreads();
    int start = bucket_base[b], ne = bucket_cnt[b];
    int c = t & 15, g = t >> 4;                     // 64 groups of 16 lanes
    int nq = (ne + 3) >> 2;
    for (int qi = g; qi < nq; qi += 64) {
        int4v q = __builtin_nontemporal_load((const int4v*)(bedges + start + (qi << 2)));
        float v0 = bf2f(h1b[(size_t)(q.x >> 8) * F_HID + c]);
        float v1 = bf2f(h1b[(size_t)(q.y >> 8) * F_HID + c]);
        float v2 = bf2f(h1b[(size_t)(q.z >> 8) * F_HID + c]);
        float v3 = bf2f(h1b[(size_t)(q.w >> 8) * F_HID + c]);
        atomicAdd(&acc[(q.x & 255) * AST + c], v0);
        atomicAdd(&acc[(q.y & 255) * AST + c], v1);
        atomicAdd(&acc[(q.z & 255) * AST + c], v2);
        atomicAdd(&acc[(q.w & 255) * AST + c], v3);
    }
    __syncthreads();
    int nodebase = b * BUCKET;
    for (int i = t; i < BUCKET * F_HID; i += 1024) {
        int row = i >> 4, cc = i & 15;
        int node = nodebase + row;
        if (node < n)
            agg1[(size_t)node * F_HID + cc] =
                dinv[node] * (acc[row * AST + cc] + bf2f(h1b[(size_t)node * F_HID + cc]));
    }
}

// ---- relu+bias1+GEMM2, h2b = bf16(dinv * h2) (stride 8, col7 = 0) ----
__global__ void k_layer2(const float* __restrict__ agg1, const float* __restrict__ b1,
                         const float* __restrict__ W2, const float* __restrict__ dinv,
                         unsigned short* __restrict__ h2b, int n) {
    int r = blockIdx.x * blockDim.x + threadIdx.x;
    if (r >= n) return;
    float z[F_HID];
    const float4* ai = (const float4*)(agg1 + (size_t)r * F_HID);
#pragma unroll
    for (int q = 0; q < 4; ++q) {
        float4 v = ai[q];
        z[q * 4 + 0] = fmaxf(v.x + b1[q * 4 + 0], 0.0f);
        z[q * 4 + 1] = fmaxf(v.y + b1[q * 4 + 1], 0.0f);
        z[q * 4 + 2] = fmaxf(v.z + b1[q * 4 + 2], 0.0f);
        z[q * 4 + 3] = fmaxf(v.w + b1[q * 4 + 3], 0.0f);
    }
    float h[F_OUT];
#pragma unroll
    for (int c = 0; c < F_OUT; ++c) h[c] = 0.0f;
#pragma unroll
    for (int k = 0; k < F_HID; ++k)
#pragma unroll
        for (int c = 0; c < F_OUT; ++c)
            h[c] = fmaf(z[k], W2[k * F_OUT + c], h[c]);
    float dv = dinv[r];
    uint4v w;
    w.x = (unsigned)f2bf(dv * h[0]) | ((unsigned)f2bf(dv * h[1]) << 16);
    w.y = (unsigned)f2bf(dv * h[2]) | ((unsigned)f2bf(dv * h[3]) << 16);
    w.z = (unsigned)f2bf(dv * h[4]) | ((unsigned)f2bf(dv * h[5]) << 16);
    w.w = (unsigned)f2bf(dv * h[6]);                    // col 7 = 0
    *(uint4v*)(h2b + (size_t)r * 8) = w;
}

// ------ agg layer 2: block(1024)/bucket, bf16 gathers (16B/edge), writes final out ------
__global__ __launch_bounds__(1024) void k_agg2(
        const int* __restrict__ bucket_base, const int* __restrict__ bucket_cnt,
        const int* __restrict__ bedges, const unsigned short* __restrict__ h2b,
        const float* __restrict__ dinv, const float* __restrict__ b2,
        float* __restrict__ out, int n) {
    __shared__ float acc[(BUCKET + 1) * AST2];      // row 128 = trash
    int b = blockIdx.x, t = threadIdx.x;
    for (int i = t; i < (BUCKET + 1) * AST2; i += 1024) acc[i] = 0.0f;
    __syncthreads();
    int start = bucket_base[b], ne = bucket_cnt[b];
    int c = t & 7, g = t >> 3;                      // 128 groups of 8 lanes
    int nq = (ne + 3) >> 2;
    for (int qi = g; qi < nq; qi += 128) {
        int4v q = __builtin_nontemporal_load((const int4v*)(bedges + start + (qi << 2)));
        float v0 = bf2f(h2b[(size_t)(q.x >> 8) * 8 + c]);
        float v1 = bf2f(h2b[(size_t)(q.y >> 8) * 8 + c]);
        float v2 = bf2f(h2b[(size_t)(q.z >> 8) * 8 + c]);
        float v3 = bf2f(h2b[(size_t)(q.w >> 8) * 8 + c]);
        atomicAdd(&acc[(q.x & 255) * AST2 + c], v0);
        atomicAdd(&acc[(q.y & 255) * AST2 + c], v1);
        atomicAdd(&acc[(q.z & 255) * AST2 + c], v2);
        atomicAdd(&acc[(q.w & 255) * AST2 + c], v3);
    }
    __syncthreads();
    int nodebase = b * BUCKET;
    for (int i = t; i < BUCKET * 8; i += 1024) {
        int row = i >> 3, cc = i & 7;
        int node = nodebase + row;
        if (node < n && cc < F_OUT)
            out[(size_t)node * F_OUT + cc] =
                dinv[node] * (acc[row * AST2 + cc] + bf2f(h2b[(size_t)node * 8 + cc])) + b2[cc];
    }
}

extern "C" void kernel_launch(void* const* d_in, const int* in_sizes, int n_in,
                              void* d_out, int out_size, void* d_ws, size_t ws_size,
                              hipStream_t stream) {
    const float* x  = (const float*)d_in[0];
    const int*   ei = (const int*)d_in[1];      // int64 in source but JAX x64 off -> int32
    const float* W1 = (const float*)d_in[2];
    const float* b1 = (const float*)d_in[3];
    const float* W2 = (const float*)d_in[4];
    const float* b2 = (const float*)d_in[5];
    float* out = (float*)d_out;

    const int n = in_sizes[0] / F_IN;       // 100000
    const int E = in_sizes[1] / 2;          // 3200000
    const int* src = ei;
    const int* dst = ei + E;

    const int NB = (n + BUCKET - 1) / BUCKET;   // 782 (must be <= MAXNB)
    const int PBLK = (E + CHUNK - 1) / CHUNK;   // 391 partition blocks

    // workspace layout (16B-aligned sections)
    size_t Np = ((size_t)n + 3) & ~(size_t)3;
    size_t Ep = ((size_t)E + 4 * MAXNB + 3) & ~(size_t)3;   // room for 4-align pads
    char* ws = (char*)d_ws;
    int*   bucket_cnt  = (int*)ws;              ws += MAXNB * 4;
    int*   bucket_base = (int*)ws;              ws += MAXNB * 4;
    int*   cursor      = (int*)ws;              ws += MAXNB * 4;
    float* dinv        = (float*)ws;            ws += Np * 4;
    int*   bedges      = (int*)ws;              ws += Ep * 4;
    unsigned short* h1b = (unsigned short*)ws;  ws += Np * F_HID * 2;   // 3.2 MB bf16
    float* agg1        = (float*)ws;            ws += Np * F_HID * 4;
    unsigned short* h2b = h1b;                  // h1b dead after k_agg1 (1.6 MB needed)

    k_zero      <<<4, 256, 0, stream>>>(bucket_cnt, NB);
    k_bhist     <<<PBLK, 256, 0, stream>>>(dst, bucket_cnt, E, NB);
    k_bscan     <<<1, 1024, 0, stream>>>(bucket_cnt, bucket_base, cursor, bedges, NB);
    k_place     <<<PBLK, 256, 0, stream>>>(src, dst, cursor, bedges, E, NB);
    k_bdeg_dinv <<<NB, 256, 0, stream>>>(bucket_base, bucket_cnt, bedges, dinv, n);
    k_gemm1     <<<(n + 255) / 256, 256, 0, stream>>>(x, W1, dinv, h1b, n);
    k_agg1      <<<NB, 1024, 0, stream>>>(bucket_base, bucket_cnt, bedges, h1b, dinv, agg1, n);
    k_layer2    <<<(n + 255) / 256, 256, 0, stream>>>(agg1, b1, W2, dinv, h2b, n);
    k_agg2      <<<NB, 1024, 0, stream>>>(bucket_base, bucket_cnt, bedges, h2b, dinv, b2, out, n);
}

// Round 6
// 560.790 us; speedup vs baseline: 1.8392x; 1.8392x over previous
//
#include <hip/hip_runtime.h>

#define F_IN 512
#define F_HID 16
#define F_OUT 7
#define BUCKET 128          // nodes per bucket
#define LB 7                // log2(BUCKET)
#define TRASH 128           // dl value for sentinel pad edges in bedges
#define PADV 128            // packed sentinel: src=0, dl=TRASH
#define CHUNK 8192          // edges per partition block
#define MAXNB 1024          // max buckets supported by scans

typedef int   int4v   __attribute__((ext_vector_type(4)));
typedef float float4v __attribute__((ext_vector_type(4)));
typedef unsigned int uint4v __attribute__((ext_vector_type(4)));

static __device__ __forceinline__ unsigned short f2bf(float f) {   // RNE
    unsigned int u = __float_as_uint(f);
    u += 0x7FFFu + ((u >> 16) & 1u);
    return (unsigned short)(u >> 16);
}
static __device__ __forceinline__ float bf2f(unsigned short s) {
    return __uint_as_float((unsigned int)s << 16);
}

// ---------------- zero int array ----------------
__global__ void k_zero(int* __restrict__ p, int n) {
    int i = blockIdx.x * blockDim.x + threadIdx.x;
    if (i < n) p[i] = 0;
}

// ---------------- bucket histogram ----------------
__global__ void k_bhist(const int* __restrict__ dst, int* __restrict__ bucket_cnt, int E, int NB) {
    __shared__ int hist[MAXNB];
    int t = threadIdx.x;
    for (int i = t; i < NB; i += 256) hist[i] = 0;
    __syncthreads();
    int base = blockIdx.x * CHUNK;
#pragma unroll
    for (int i = 0; i < CHUNK / 256; ++i) {
        int e = base + i * 256 + t;
        if (e < E) atomicAdd(&hist[__builtin_nontemporal_load(dst + e) >> LB], 1);
    }
    __syncthreads();
    for (int i = t; i < NB; i += 256)
        if (hist[i]) atomicAdd(&bucket_cnt[i], hist[i]);
}

// ---- scan 1: exclusive scan of 4-aligned bucket counts + sentinel pad tails ----
__global__ void k_bscan1(const int* __restrict__ bucket_cnt, int* __restrict__ bucket_base,
                         int* __restrict__ cursor, int* __restrict__ bedges, int NB) {
    __shared__ int sm[MAXNB];
    int t = threadIdx.x;                       // 1024 threads
    int c = (t < NB) ? bucket_cnt[t] : 0;
    int ca = (c + 3) & ~3;
    sm[t] = ca;
    __syncthreads();
    for (int off = 1; off < MAXNB; off <<= 1) {
        int v = sm[t];
        int add = (t >= off) ? sm[t - off] : 0;
        __syncthreads();
        sm[t] = v + add;
        __syncthreads();
    }
    if (t < NB) {
        int base = sm[t] - ca;
        bucket_base[t] = base;
        cursor[t] = base;
        for (int i = c; i < ca; ++i) bedges[base + i] = PADV;
    }
}

// ---------------- partition: packed edges into bucket segments ----------------
__global__ void k_place(const int* __restrict__ src, const int* __restrict__ dst,
                        int* __restrict__ cursor, int* __restrict__ bedges, int E, int NB) {
    __shared__ int hist[MAXNB];
    __shared__ int lcur[MAXNB];
    int t = threadIdx.x;
    for (int i = t; i < NB; i += 256) hist[i] = 0;
    __syncthreads();
    int base = blockIdx.x * CHUNK;
#pragma unroll
    for (int i = 0; i < CHUNK / 256; ++i) {
        int e = base + i * 256 + t;
        if (e < E) atomicAdd(&hist[__builtin_nontemporal_load(dst + e) >> LB], 1);
    }
    __syncthreads();
    for (int i = t; i < NB; i += 256)
        lcur[i] = hist[i] ? atomicAdd(&cursor[i], hist[i]) : 0;
    __syncthreads();
#pragma unroll
    for (int i = 0; i < CHUNK / 256; ++i) {
        int e = base + i * 256 + t;
        if (e < E) {
            int d = __builtin_nontemporal_load(dst + e);
            int s = __builtin_nontemporal_load(src + e);
            int b = d >> LB;
            int pos = atomicAdd(&lcur[b], 1);
            __builtin_nontemporal_store((s << 8) | (d & (BUCKET - 1)), bedges + pos);
        }
    }
}

// ---- per-bucket: degree hist -> dinv, within-bucket 4-padded offsets, bucket padded size ----
__global__ void k_pcount(const int* __restrict__ bucket_base, const int* __restrict__ bucket_cnt,
                         const int* __restrict__ bedges, float* __restrict__ dinv,
                         int* __restrict__ node_off, int* __restrict__ bucket_psize, int n) {
    __shared__ int cnt[TRASH + 8];             // bins 0..128 (128 = sentinel trash)
    __shared__ int sc[BUCKET];
    int b = blockIdx.x, t = threadIdx.x;       // 256 threads
    for (int i = t; i < TRASH + 8; i += 256) cnt[i] = 0;
    __syncthreads();
    int base = bucket_base[b], ne = bucket_cnt[b];
    int nqq = (ne + 3) >> 2;
    for (int qi = t; qi < nqq; qi += 256) {
        int4v q = __builtin_nontemporal_load((const int4v*)(bedges + base + (qi << 2)));
        atomicAdd(&cnt[q.x & 255], 1);
        atomicAdd(&cnt[q.y & 255], 1);
        atomicAdd(&cnt[q.z & 255], 1);
        atomicAdd(&cnt[q.w & 255], 1);
    }
    __syncthreads();
    int p = 0;
    if (t < BUCKET) { p = (cnt[t] + 3) & ~3; sc[t] = p; }
    __syncthreads();
    for (int off = 1; off < BUCKET; off <<= 1) {
        int v = 0;
        if (t < BUCKET) { v = sc[t]; if (t >= off) v += sc[t - off]; }
        __syncthreads();
        if (t < BUCKET) sc[t] = v;
        __syncthreads();
    }
    if (t < BUCKET) {
        int node = b * BUCKET + t;
        if (node < n) {
            dinv[node] = rsqrtf((float)(cnt[t] + 1));   // +1 self-loop
            node_off[node] = sc[t] - p;                 // within-bucket padded offset (woff)
        }
        if (t == BUCKET - 1) bucket_psize[b] = sc[t];
    }
}

// ---- scan 2: exclusive scan of padded bucket sizes -> pbase ----
__global__ void k_bscan2(const int* __restrict__ bucket_psize, int* __restrict__ pbase, int NB) {
    __shared__ int sm[MAXNB];
    int t = threadIdx.x;                       // 1024 threads
    int c = (t < NB) ? bucket_psize[t] : 0;
    sm[t] = c;
    __syncthreads();
    for (int off = 1; off < MAXNB; off <<= 1) {
        int v = sm[t];
        int add = (t >= off) ? sm[t - off] : 0;
        __syncthreads();
        sm[t] = v + add;
        __syncthreads();
    }
    if (t < NB) pbase[t] = sm[t] - c;
}

// ---- per-bucket counting sort by dl: bedges -> bedges2 (src only, per-node 4-padded runs) ----
__global__ void k_sort(const int* __restrict__ bucket_base, const int* __restrict__ bucket_cnt,
                       const int* __restrict__ pbase, const int* __restrict__ bedges,
                       int* __restrict__ bedges2, int* __restrict__ node_off,
                       int* __restrict__ node_nq, int n) {
    __shared__ int cur[BUCKET];
    __shared__ int woffs[BUCKET];
    int b = blockIdx.x, t = threadIdx.x;       // 256 threads
    int pb = pbase[b];
    if (t < BUCKET) {
        int node = b * BUCKET + t;
        int w = (node < n) ? node_off[node] : 0;
        woffs[t] = w;
        cur[t] = w;
    }
    __syncthreads();
    int base = bucket_base[b], ne = bucket_cnt[b];
    int nqq = (ne + 3) >> 2;
    for (int qi = t; qi < nqq; qi += 256) {
        int4v q = __builtin_nontemporal_load((const int4v*)(bedges + base + (qi << 2)));
        int v, dl, pos;
        v = q.x; dl = v & 255;
        if (dl < BUCKET) { pos = atomicAdd(&cur[dl], 1); bedges2[pb + pos] = v >> 8; }
        v = q.y; dl = v & 255;
        if (dl < BUCKET) { pos = atomicAdd(&cur[dl], 1); bedges2[pb + pos] = v >> 8; }
        v = q.z; dl = v & 255;
        if (dl < BUCKET) { pos = atomicAdd(&cur[dl], 1); bedges2[pb + pos] = v >> 8; }
        v = q.w; dl = v & 255;
        if (dl < BUCKET) { pos = atomicAdd(&cur[dl], 1); bedges2[pb + pos] = v >> 8; }
    }
    __syncthreads();
    if (t < BUCKET) {
        int node = b * BUCKET + t;
        if (node < n) {
            int w = woffs[t];
            int endc = cur[t];
            int cnt = endc - w;
            int p = (cnt + 3) & ~3;
            for (int i = endc; i < w + p; ++i) bedges2[pb + i] = n;   // sentinel -> zero row
            node_off[node] = pb + w;                                  // now GLOBAL offset
            node_nq[node] = p >> 2;
        }
    }
}

// -------- GEMM1: h1b = bf16( dinv[r] * (x @ W1) ); row n = zeros --------
__global__ void k_gemm1(const float* __restrict__ x, const float* __restrict__ W,
                        const float* __restrict__ dinv, unsigned short* __restrict__ h1b, int n) {
    int r = blockIdx.x * blockDim.x + threadIdx.x;
    if (r > n) return;
    uint4v* o = (uint4v*)(h1b + (size_t)r * F_HID);
    if (r == n) {                               // sentinel zero row
        uint4v z = {0u, 0u, 0u, 0u};
        o[0] = z; o[1] = z;
        return;
    }
    float acc[F_HID];
#pragma unroll
    for (int c = 0; c < F_HID; ++c) acc[c] = 0.0f;
    const float4v* xr = (const float4v*)(x + (size_t)r * F_IN);
    for (int k4 = 0; k4 < F_IN / 4; ++k4) {
        float4v xv = xr[k4];
        int k = k4 * 4;
#pragma unroll
        for (int c = 0; c < F_HID; ++c) {
            acc[c] = fmaf(xv.x, W[(k + 0) * F_HID + c], acc[c]);
            acc[c] = fmaf(xv.y, W[(k + 1) * F_HID + c], acc[c]);
            acc[c] = fmaf(xv.z, W[(k + 2) * F_HID + c], acc[c]);
            acc[c] = fmaf(xv.w, W[(k + 3) * F_HID + c], acc[c]);
        }
    }
    float dv = dinv[r];
    uint4v w0, w1;
    w0.x = (unsigned)f2bf(dv * acc[0])  | ((unsigned)f2bf(dv * acc[1])  << 16);
    w0.y = (unsigned)f2bf(dv * acc[2])  | ((unsigned)f2bf(dv * acc[3])  << 16);
    w0.z = (unsigned)f2bf(dv * acc[4])  | ((unsigned)f2bf(dv * acc[5])  << 16);
    w0.w = (unsigned)f2bf(dv * acc[6])  | ((unsigned)f2bf(dv * acc[7])  << 16);
    w1.x = (unsigned)f2bf(dv * acc[8])  | ((unsigned)f2bf(dv * acc[9])  << 16);
    w1.y = (unsigned)f2bf(dv * acc[10]) | ((unsigned)f2bf(dv * acc[11]) << 16);
    w1.z = (unsigned)f2bf(dv * acc[12]) | ((unsigned)f2bf(dv * acc[13]) << 16);
    w1.w = (unsigned)f2bf(dv * acc[14]) | ((unsigned)f2bf(dv * acc[15]) << 16);
    o[0] = w0;
    o[1] = w1;
}

// ------ agg layer 1: 16 lanes/node, CSR quads, REGISTER accumulation, no atomics ------
__global__ __launch_bounds__(1024) void k_agg1(
        const int* __restrict__ node_off, const int* __restrict__ node_nq,
        const int* __restrict__ bedges2, const unsigned short* __restrict__ h1b,
        const float* __restrict__ dinv, float* __restrict__ agg1, int n) {
    int tg = blockIdx.x * 1024 + threadIdx.x;
    int node = tg >> 4, c = tg & 15;
    if (node >= n) return;
    int off = node_off[node], nq = node_nq[node];
    float acc = bf2f(h1b[(size_t)node * F_HID + c]);    // self-loop (pre-scaled)
    for (int q = 0; q < nq; ++q) {
        int4v s = *(const int4v*)(bedges2 + off + (q << 2));
        float v0 = bf2f(h1b[(size_t)s.x * F_HID + c]);
        float v1 = bf2f(h1b[(size_t)s.y * F_HID + c]);
        float v2 = bf2f(h1b[(size_t)s.z * F_HID + c]);
        float v3 = bf2f(h1b[(size_t)s.w * F_HID + c]);
        acc += v0 + v1 + v2 + v3;
    }
    agg1[(size_t)node * F_HID + c] = dinv[node] * acc;
}

// ---- relu+bias1+GEMM2, h2b = bf16(dinv * h2) (stride 8, col7 = 0); row n zeros ----
__global__ void k_layer2(const float* __restrict__ agg1, const float* __restrict__ b1,
                         const float* __restrict__ W2, const float* __restrict__ dinv,
                         unsigned short* __restrict__ h2b, int n) {
    int r = blockIdx.x * blockDim.x + threadIdx.x;
    if (r > n) return;
    if (r == n) {
        uint4v z = {0u, 0u, 0u, 0u};
        *(uint4v*)(h2b + (size_t)r * 8) = z;
        return;
    }
    float z[F_HID];
    const float4* ai = (const float4*)(agg1 + (size_t)r * F_HID);
#pragma unroll
    for (int q = 0; q < 4; ++q) {
        float4 v = ai[q];
        z[q * 4 + 0] = fmaxf(v.x + b1[q * 4 + 0], 0.0f);
        z[q * 4 + 1] = fmaxf(v.y + b1[q * 4 + 1], 0.0f);
        z[q * 4 + 2] = fmaxf(v.z + b1[q * 4 + 2], 0.0f);
        z[q * 4 + 3] = fmaxf(v.w + b1[q * 4 + 3], 0.0f);
    }
    float h[F_OUT];
#pragma unroll
    for (int c = 0; c < F_OUT; ++c) h[c] = 0.0f;
#pragma unroll
    for (int k = 0; k < F_HID; ++k)
#pragma unroll
        for (int c = 0; c < F_OUT; ++c)
            h[c] = fmaf(z[k], W2[k * F_OUT + c], h[c]);
    float dv = dinv[r];
    uint4v w;
    w.x = (unsigned)f2bf(dv * h[0]) | ((unsigned)f2bf(dv * h[1]) << 16);
    w.y = (unsigned)f2bf(dv * h[2]) | ((unsigned)f2bf(dv * h[3]) << 16);
    w.z = (unsigned)f2bf(dv * h[4]) | ((unsigned)f2bf(dv * h[5]) << 16);
    w.w = (unsigned)f2bf(dv * h[6]);
    *(uint4v*)(h2b + (size_t)r * 8) = w;
}

// ------ agg layer 2: 8 lanes/node, CSR quads, register accumulation, writes out ------
__global__ __launch_bounds__(1024) void k_agg2(
        const int* __restrict__ node_off, const int* __restrict__ node_nq,
        const int* __restrict__ bedges2, const unsigned short* __restrict__ h2b,
        const float* __restrict__ dinv, const float* __restrict__ b2,
        float* __restrict__ out, int n) {
    int tg = blockIdx.x * 1024 + threadIdx.x;
    int node = tg >> 3, c = tg & 7;
    if (node >= n) return;
    int off = node_off[node], nq = node_nq[node];
    float acc = bf2f(h2b[(size_t)node * 8 + c]);        // self-loop (col7 = 0)
    for (int q = 0; q < nq; ++q) {
        int4v s = *(const int4v*)(bedges2 + off + (q << 2));
        float v0 = bf2f(h2b[(size_t)s.x * 8 + c]);
        float v1 = bf2f(h2b[(size_t)s.y * 8 + c]);
        float v2 = bf2f(h2b[(size_t)s.z * 8 + c]);
        float v3 = bf2f(h2b[(size_t)s.w * 8 + c]);
        acc += v0 + v1 + v2 + v3;
    }
    if (c < F_OUT)
        out[(size_t)node * F_OUT + c] = dinv[node] * acc + b2[c];
}

extern "C" void kernel_launch(void* const* d_in, const int* in_sizes, int n_in,
                              void* d_out, int out_size, void* d_ws, size_t ws_size,
                              hipStream_t stream) {
    const float* x  = (const float*)d_in[0];
    const int*   ei = (const int*)d_in[1];      // int64 in source but JAX x64 off -> int32
    const float* W1 = (const float*)d_in[2];
    const float* b1 = (const float*)d_in[3];
    const float* W2 = (const float*)d_in[4];
    const float* b2 = (const float*)d_in[5];
    float* out = (float*)d_out;

    const int n = in_sizes[0] / F_IN;       // 100000
    const int E = in_sizes[1] / 2;          // 3200000
    const int* src = ei;
    const int* dst = ei + E;

    const int NB = (n + BUCKET - 1) / BUCKET;   // 782 (<= MAXNB)
    const int PBLK = (E + CHUNK - 1) / CHUNK;

    // workspace layout (16B-aligned sections)
    size_t Np = ((size_t)n + 3) & ~(size_t)3;
    char* ws = (char*)d_ws;
    int*   bucket_cnt   = (int*)ws;             ws += MAXNB * 4;
    int*   bucket_base  = (int*)ws;             ws += MAXNB * 4;
    int*   cursor       = (int*)ws;             ws += MAXNB * 4;
    int*   bucket_psize = (int*)ws;             ws += MAXNB * 4;
    int*   pbase        = (int*)ws;             ws += MAXNB * 4;
    float* dinv         = (float*)ws;           ws += Np * 4;
    int*   node_off     = (int*)ws;             ws += Np * 4;
    int*   node_nq      = (int*)ws;             ws += Np * 4;
    int*   bedges       = (int*)ws;             ws += ((size_t)E + 4 * MAXNB) * 4;
    int*   bedges2      = (int*)ws;             ws += ((size_t)E + 4 * Np) * 4;
    unsigned short* h1b = (unsigned short*)ws;  ws += (Np + 4) * F_HID * 2;
    float* agg1         = (float*)bedges;       // bedges dead after k_sort; 6.4MB <= 13MB
    unsigned short* h2b = h1b;                  // h1b dead after k_agg1

    k_zero   <<<4, 256, 0, stream>>>(bucket_cnt, NB);
    k_bhist  <<<PBLK, 256, 0, stream>>>(dst, bucket_cnt, E, NB);
    k_bscan1 <<<1, 1024, 0, stream>>>(bucket_cnt, bucket_base, cursor, bedges, NB);
    k_place  <<<PBLK, 256, 0, stream>>>(src, dst, cursor, bedges, E, NB);
    k_pcount <<<NB, 256, 0, stream>>>(bucket_base, bucket_cnt, bedges, dinv, node_off, bucket_psize, n);
    k_bscan2 <<<1, 1024, 0, stream>>>(bucket_psize, pbase, NB);
    k_sort   <<<NB, 256, 0, stream>>>(bucket_base, bucket_cnt, pbase, bedges, bedges2, node_off, node_nq, n);
    k_gemm1  <<<(n + 1 + 255) / 256, 256, 0, stream>>>(x, W1, dinv, h1b, n);
    k_agg1   <<<((size_t)n * 16 + 1023) / 1024, 1024, 0, stream>>>(node_off, node_nq, bedges2, h1b, dinv, agg1, n);
    k_layer2 <<<(n + 1 + 255) / 256, 256, 0, stream>>>(agg1, b1, W2, dinv, h2b, n);
    k_agg2   <<<((size_t)n * 8 + 1023) / 1024, 1024, 0, stream>>>(node_off, node_nq, bedges2, h2b, dinv, b2, out, n);
}